// Round 1
// 465.830 us; speedup vs baseline: 1.0584x; 1.0584x over previous
//
#include <hip/hip_runtime.h>
#include <hip/hip_fp16.h>
#include <math.h>

#define T_DIM 4096
#define MOL_N 2048
#define DESC_N 6
#define NSOL_N 5
#define H_DIM 2048
#define DBLK 2054
#define D_IN_N 12325
#define GK 2048

typedef _Float16 f16x8 __attribute__((ext_vector_type(8)));
typedef float f32x4 __attribute__((ext_vector_type(4)));

// tanh-form GELU as x * sigmoid(1.5957691x + 0.0713548x^3).
__device__ __forceinline__ float gelu_f(float x) {
    float v = x * (1.5957691f + 0.0713548f * x * x);
    float e = __expf(-v);
    return x / (1.0f + e);
}

// ---- Kernel 1: prep = conv (blocks 0..16383) + fold (blocks 16384..20479) ----
__global__ __launch_bounds__(256) void prep_kernel(
    const float* __restrict__ W1f, const float* __restrict__ W2f,
    const float* __restrict__ W1b, const float* __restrict__ W2b,
    _Float16* __restrict__ Wc,
    const float* __restrict__ W0f, const float* __restrict__ W0b,
    const float* __restrict__ b0f, const float* __restrict__ b0b,
    const float* __restrict__ mol, const float* __restrict__ sv,
    float* __restrict__ fold_f, float* __restrict__ fold_b)
{
    __shared__ float red[4][6];
    const int bid = blockIdx.x;
    const int tid = threadIdx.x;

    if (bid < 16384) {
        // conv: fp32 -> fp16 for W1/W2 both trunks
        const int z = bid >> 12;
        const float* __restrict__ src = (z == 0) ? W1f : (z == 1) ? W2f : (z == 2) ? W1b : W2b;
        _Float16* __restrict__ dst = Wc + (size_t)z * H_DIM * H_DIM;
        const int idx = (bid & 4095) * 256 + tid;
        float4 v = ((const float4*)src)[idx];
        struct h4 { _Float16 a, b, c, d; };
        h4 o;
        o.a = (_Float16)v.x; o.b = (_Float16)v.y; o.c = (_Float16)v.z; o.d = (_Float16)v.w;
        ((h4*)dst)[idx] = o;
        return;
    }

    // fold: layer-0 weights against static input structure
    const int fb = bid - 16384;
    const int h = fb & 2047;
    const int z = fb >> 11;
    const float* __restrict__ W0 = z ? W0b : W0f;
    const float* __restrict__ b0 = z ? b0b : b0f;
    float* __restrict__ fold = z ? fold_b : fold_f;
    const float* __restrict__ row = W0 + (size_t)h * D_IN_N;

    float acc[6] = {0.f, 0.f, 0.f, 0.f, 0.f, 0.f};
    #pragma unroll
    for (int i = 0; i < 8; ++i) {
        const int c = tid + i * 256;
        const float m = mol[c];
        acc[0] += row[c] * m;
        #pragma unroll
        for (int s = 0; s < NSOL_N; ++s)
            acc[1 + s] += row[DBLK * (s + 1) + c] * sv[s * MOL_N + c];
    }
    #pragma unroll
    for (int i = 0; i < 6; ++i) {
        float v = acc[i];
        #pragma unroll
        for (int off = 32; off >= 1; off >>= 1)
            v += __shfl_xor(v, off, 64);
        acc[i] = v;
    }
    const int lane = tid & 63, wave = tid >> 6;
    if (lane == 0) {
        #pragma unroll
        for (int i = 0; i < 6; ++i) red[wave][i] = acc[i];
    }
    __syncthreads();
    if (tid < 6) {
        float s = red[0][tid] + red[1][tid] + red[2][tid] + red[3][tid];
        if (tid == 0) fold[h] = s + b0[h];
        else fold[(size_t)tid * H_DIM + h] = s;
    }
    if (tid >= 64 && tid < 70) {
        int j = tid - 64;
        float w = row[MOL_N + j];
        #pragma unroll
        for (int s = 0; s < NSOL_N; ++s) w += row[DBLK * (s + 1) + MOL_N + j];
        fold[(size_t)(6 + j) * H_DIM + h] = w;
    }
    if (tid == 70) fold[(size_t)12 * H_DIM + h] = row[D_IN_N - 1];
}

// ---- Kernel 2: h0 = gelu(folded layer-0), store fp16 ----
__global__ __launch_bounds__(256) void h0_kernel(
    const float* __restrict__ fold_f, const float* __restrict__ fold_b,
    const float* __restrict__ desc, const float* __restrict__ sol,
    const float* __restrict__ rf,
    _Float16* __restrict__ h0f, _Float16* __restrict__ h0b)
{
    const int z = blockIdx.z;
    const float* __restrict__ fold = z ? fold_b : fold_f;
    _Float16* __restrict__ h0 = z ? h0b : h0f;
    const int h = blockIdx.x * 256 + threadIdx.x;
    const int tbase = blockIdx.y * 64;

    const float c0 = fold[h];
    float u[NSOL_N], wd[DESC_N];
    #pragma unroll
    for (int s = 0; s < NSOL_N; ++s) u[s] = fold[(size_t)(1 + s) * H_DIM + h];
    #pragma unroll
    for (int j = 0; j < DESC_N; ++j) wd[j] = fold[(size_t)(6 + j) * H_DIM + h];
    const float wp = fold[(size_t)12 * H_DIM + h];

    for (int i = 0; i < 64; ++i) {
        const int t = tbase + i;
        float pv;
        if (z == 0) pv = (t == 0) ? 0.5f : rf[t - 1];
        else        pv = (t == T_DIM - 1) ? 0.5f : rf[t + 1];
        float pre = c0 + wp * pv;
        #pragma unroll
        for (int s = 0; s < NSOL_N; ++s) pre += u[s] * sol[t * NSOL_N + s];
        #pragma unroll
        for (int j = 0; j < DESC_N; ++j) pre += wd[j] * desc[t * DESC_N + j];
        h0[(size_t)t * H_DIM + h] = (_Float16)gelu_f(pre);
    }
}

// ---- 256x256-tile, 8-wave, BK=32, 4-deep ring pipelined GEMM core ----
// Counted vmcnt(8) keeps 2 tiles (8 loads/thread) in flight across barriers
// (T3+T4). One s_barrier per K-step. Tile k+3 staged into ring slot (k-1)&3,
// whose reads are drained (trailing lgkmcnt(0)) before any wave's next
// barrier -> race-free. Global-source XOR swizzle c^=((r>>1)&3) with linear
// LDS dest gives 2-way (free) bank aliasing on ds_read_b128.
__device__ __forceinline__ void gemm_core256(
    const _Float16* __restrict__ A, const _Float16* __restrict__ W,
    const int m0, const int n0, char* sc, f32x4 (&acc)[8][4])
{
    const int tid = threadIdx.x;
    const int wave = tid >> 6;
    const int lane = tid & 63;
    const int t15 = lane & 15;
    const int quad = lane >> 4;
    const int wr = wave >> 2;   // 0..1 : 128-row half
    const int wc = wave & 3;    // 0..3 : 64-col quarter
    const int poff = (quad ^ ((t15 >> 1) & 3)) * 16;
    const int aoff0 = (wr * 128 + t15) * 64 + poff;
    const int boff0 = 16384 + (wc * 64 + t15) * 64 + poff;

    const _Float16* gsrc[4];
    #pragma unroll
    for (int ld = 0; ld < 4; ++ld) {
        const int j = (ld & 1) * 512 + tid;       // chunk index within A or B
        const int r = j >> 2;                     // row 0..255
        const int c = (j & 3) ^ ((r >> 1) & 3);   // pre-swizzled k-chunk
        gsrc[ld] = ((ld < 2) ? (A + (size_t)(m0 + r) * GK)
                             : (W + (size_t)(n0 + r) * GK)) + c * 8;
    }

    #pragma unroll
    for (int mi = 0; mi < 8; ++mi)
        #pragma unroll
        for (int ni = 0; ni < 4; ++ni)
            acc[mi][ni] = (f32x4){0.f, 0.f, 0.f, 0.f};

#define STAGE_T(kt, b) do { \
    char* _db = sc + (b) * 32768; \
    const int _ko = (kt) * 32; \
    __builtin_amdgcn_global_load_lds((const __attribute__((address_space(1))) void*)(gsrc[0] + _ko), (__attribute__((address_space(3))) void*)(_db + wave * 1024), 16, 0, 0); \
    __builtin_amdgcn_global_load_lds((const __attribute__((address_space(1))) void*)(gsrc[1] + _ko), (__attribute__((address_space(3))) void*)(_db + 8192 + wave * 1024), 16, 0, 0); \
    __builtin_amdgcn_global_load_lds((const __attribute__((address_space(1))) void*)(gsrc[2] + _ko), (__attribute__((address_space(3))) void*)(_db + 16384 + wave * 1024), 16, 0, 0); \
    __builtin_amdgcn_global_load_lds((const __attribute__((address_space(1))) void*)(gsrc[3] + _ko), (__attribute__((address_space(3))) void*)(_db + 24576 + wave * 1024), 16, 0, 0); \
} while (0)

#define COMPUTE_T(b) do { \
    const char* _db = sc + (b) * 32768; \
    f16x8 aF[8], bF[4]; \
    _Pragma("unroll") \
    for (int mi = 0; mi < 8; ++mi) aF[mi] = *(const f16x8*)(_db + aoff0 + mi * 1024); \
    _Pragma("unroll") \
    for (int ni = 0; ni < 4; ++ni) bF[ni] = *(const f16x8*)(_db + boff0 + ni * 1024); \
    __builtin_amdgcn_s_setprio(1); \
    _Pragma("unroll") \
    for (int mi = 0; mi < 8; ++mi) { \
        _Pragma("unroll") \
        for (int ni = 0; ni < 4; ++ni) \
            acc[mi][ni] = __builtin_amdgcn_mfma_f32_16x16x32_f16(aF[mi], bF[ni], acc[mi][ni], 0, 0, 0); \
    } \
    __builtin_amdgcn_s_setprio(0); \
    asm volatile("s_waitcnt lgkmcnt(0)" ::: "memory"); \
} while (0)

    STAGE_T(0, 0); STAGE_T(1, 1); STAGE_T(2, 2);

    #pragma unroll 1
    for (int k4 = 0; k4 < 60; k4 += 4) {
        asm volatile("s_waitcnt vmcnt(8)" ::: "memory");
        __builtin_amdgcn_s_barrier();
        STAGE_T(k4 + 3, 3); COMPUTE_T(0);
        asm volatile("s_waitcnt vmcnt(8)" ::: "memory");
        __builtin_amdgcn_s_barrier();
        STAGE_T(k4 + 4, 0); COMPUTE_T(1);
        asm volatile("s_waitcnt vmcnt(8)" ::: "memory");
        __builtin_amdgcn_s_barrier();
        STAGE_T(k4 + 5, 1); COMPUTE_T(2);
        asm volatile("s_waitcnt vmcnt(8)" ::: "memory");
        __builtin_amdgcn_s_barrier();
        STAGE_T(k4 + 6, 2); COMPUTE_T(3);
    }
    // k = 60 (stage last tile), 61, 62, 63 with draining waits
    asm volatile("s_waitcnt vmcnt(8)" ::: "memory");
    __builtin_amdgcn_s_barrier();
    STAGE_T(63, 3); COMPUTE_T(0);
    asm volatile("s_waitcnt vmcnt(8)" ::: "memory");
    __builtin_amdgcn_s_barrier();
    COMPUTE_T(1);
    asm volatile("s_waitcnt vmcnt(4)" ::: "memory");
    __builtin_amdgcn_s_barrier();
    COMPUTE_T(2);
    asm volatile("s_waitcnt vmcnt(0)" ::: "memory");
    __builtin_amdgcn_s_barrier();
    COMPUTE_T(3);

#undef STAGE_T
#undef COMPUTE_T
}

// ---- Kernel 3: GEMM layer-1, C = gelu(A @ W^T + bias), fp16 out ----
__global__ __launch_bounds__(512, 2) void gemm1_kernel(
    const _Float16* __restrict__ Af, const _Float16* __restrict__ Ab,
    const _Float16* __restrict__ Wfp, const _Float16* __restrict__ Wbp,
    const float* __restrict__ bfp, const float* __restrict__ bbp,
    _Float16* __restrict__ Cf, _Float16* __restrict__ Cb)
{
    __shared__ _Float16 smem[65536];   // 128 KiB: 4-slot ring of (A 16K + B 16K)
    char* sc = (char*)smem;
    const int bid = blockIdx.x;
    const int xcd = bid & 7;
    const int slot = bid >> 3;
    const int z = xcd & 1;
    const int q = xcd >> 1;
    const int m0 = (q * 4 + (slot & 3)) * 256;
    const int n0 = (slot >> 2) * 256;

    const _Float16* __restrict__ A = z ? Ab : Af;
    const _Float16* __restrict__ W = z ? Wbp : Wfp;
    const float* __restrict__ bias = z ? bbp : bfp;
    _Float16* __restrict__ C = z ? Cb : Cf;

    f32x4 acc[8][4];
    gemm_core256(A, W, m0, n0, sc, acc);

    const int tid = threadIdx.x;
    const int wave = tid >> 6, lane = tid & 63;
    const int colC = lane & 15, quad = lane >> 4;
    const int wr = wave >> 2, wc = wave & 3;
    #pragma unroll
    for (int ni = 0; ni < 4; ++ni) {
        const int n = n0 + wc * 64 + ni * 16 + colC;
        const float bv = bias[n];
        #pragma unroll
        for (int mi = 0; mi < 8; ++mi) {
            const int mb = m0 + wr * 128 + mi * 16 + quad * 4;
            #pragma unroll
            for (int r = 0; r < 4; ++r)
                C[(size_t)(mb + r) * H_DIM + n] = (_Float16)gelu_f(acc[mi][ni][r] + bv);
        }
    }
}

// ---- Kernel 4: GEMM layer-2 with FUSED output head ----
// Epilogue: gelu in fp32, dot with Wo over this block's 256 n-cols,
// shuffle-reduce over colC lanes, LDS cross-wave reduce, one partial
// store per row per block (no atomics, no memset needed).
__global__ __launch_bounds__(512, 2) void gemm_out_kernel(
    const _Float16* __restrict__ Af, const _Float16* __restrict__ Ab,
    const _Float16* __restrict__ Wfp, const _Float16* __restrict__ Wbp,
    const float* __restrict__ bfp, const float* __restrict__ bbp,
    const float* __restrict__ Wof, const float* __restrict__ Wob,
    float* __restrict__ partial)
{
    __shared__ _Float16 smem[65536];
    char* sc = (char*)smem;
    const int bid = blockIdx.x;
    const int xcd = bid & 7;
    const int slot = bid >> 3;
    const int z = xcd & 1;
    const int q = xcd >> 1;
    const int m0 = (q * 4 + (slot & 3)) * 256;
    const int n0 = (slot >> 2) * 256;

    const _Float16* __restrict__ A = z ? Ab : Af;
    const _Float16* __restrict__ W = z ? Wbp : Wfp;
    const float* __restrict__ bias = z ? bbp : bfp;
    const float* __restrict__ Wo = z ? Wob : Wof;

    f32x4 acc[8][4];
    gemm_core256(A, W, m0, n0, sc, acc);

    const int tid = threadIdx.x;
    const int wave = tid >> 6, lane = tid & 63;
    const int colC = lane & 15, quad = lane >> 4;
    const int wr = wave >> 2, wc = wave & 3;

    float bv[4], wo[4];
    #pragma unroll
    for (int ni = 0; ni < 4; ++ni) {
        const int n = n0 + wc * 64 + ni * 16 + colC;
        bv[ni] = bias[n];
        wo[ni] = Wo[n];
    }

    __syncthreads();                 // all waves done with smem ring
    float* red = (float*)sc;         // [4 wc][256 rows]
    #pragma unroll
    for (int mi = 0; mi < 8; ++mi) {
        #pragma unroll
        for (int r = 0; r < 4; ++r) {
            float s = 0.f;
            #pragma unroll
            for (int ni = 0; ni < 4; ++ni)
                s += gelu_f(acc[mi][ni][r] + bv[ni]) * wo[ni];
            s += __shfl_xor(s, 1, 64);
            s += __shfl_xor(s, 2, 64);
            s += __shfl_xor(s, 4, 64);
            s += __shfl_xor(s, 8, 64);
            if (colC == 0)
                red[wc * 256 + wr * 128 + mi * 16 + quad * 4 + r] = s;
        }
    }
    __syncthreads();
    if (tid < 256) {
        float v = red[tid] + red[256 + tid] + red[512 + tid] + red[768 + tid];
        const int n_tile = slot >> 2;
        partial[((size_t)z * 8 + n_tile) * T_DIM + m0 + tid] = v;
    }
}

// ---- Kernel 5: finalize — sum n-tile partials + bias + clip ----
__global__ __launch_bounds__(256) void finalize_kernel(
    const float* __restrict__ partial,
    const float* __restrict__ bof, const float* __restrict__ bob,
    float* __restrict__ out)
{
    const int idx = blockIdx.x * 256 + threadIdx.x;   // 0..8191
    const int z = idx >> 12;
    const int row = idx & 4095;
    float v = z ? bob[0] : bof[0];
    #pragma unroll
    for (int nt = 0; nt < 8; ++nt)
        v += partial[((size_t)z * 8 + nt) * T_DIM + row];
    v = fminf(fmaxf(v, 1e-4f), 1.0f - 1e-4f);
    out[idx] = v;
}

extern "C" void kernel_launch(void* const* d_in, const int* in_sizes, int n_in,
                              void* d_out, int out_size, void* d_ws, size_t ws_size,
                              hipStream_t stream)
{
    (void)in_sizes; (void)n_in; (void)out_size; (void)ws_size;
    const float* mol = (const float*)d_in[0];
    const float* sol = (const float*)d_in[1];
    const float* desc = (const float*)d_in[2];
    const float* rf  = (const float*)d_in[3];
    const float* sv  = (const float*)d_in[4];
    const float* Wf0 = (const float*)d_in[5];
    const float* Wf1 = (const float*)d_in[6];
    const float* Wf2 = (const float*)d_in[7];
    const float* Wof = (const float*)d_in[8];
    const float* Wb0 = (const float*)d_in[9];
    const float* Wb1 = (const float*)d_in[10];
    const float* Wb2 = (const float*)d_in[11];
    const float* Wob = (const float*)d_in[12];
    const float* bf0 = (const float*)d_in[13];
    const float* bf1 = (const float*)d_in[14];
    const float* bf2 = (const float*)d_in[15];
    const float* bof = (const float*)d_in[16];
    const float* bb0 = (const float*)d_in[17];
    const float* bb1 = (const float*)d_in[18];
    const float* bb2 = (const float*)d_in[19];
    const float* bob = (const float*)d_in[20];
    float* out = (float*)d_out;

    char* ws = (char*)d_ws;
    float* fold_f = (float*)(ws + 0);          // 13*2048*4 = 106496 B
    float* fold_b = (float*)(ws + 131072);
    _Float16* Wc = (_Float16*)(ws + 262144);   // 4 x 2048*2048 fp16 = 33554432 B
    const size_t WSZ = (size_t)H_DIM * H_DIM;
    _Float16* W1f_c = Wc;
    _Float16* W2f_c = Wc + WSZ;
    _Float16* W1b_c = Wc + 2 * WSZ;
    _Float16* W2b_c = Wc + 3 * WSZ;
    const size_t HSZ = (size_t)T_DIM * H_DIM;  // 16777216 B fp16 each
    _Float16* h0f = (_Float16*)(ws + 33816576);
    _Float16* h0b = h0f + HSZ;
    _Float16* h1f = (_Float16*)(ws + 33816576 + 2 * 16777216);
    _Float16* h1b = h1f + HSZ;
    float* partial = (float*)(ws + 33816576);  // reuse h0f region (dead after gemm1); 256 KB
    // total ws use: 33816576 + 4*16777216 = 100,925,440 B

    prep_kernel<<<dim3(20480), 256, 0, stream>>>(
        Wf1, Wf2, Wb1, Wb2, Wc, Wf0, Wb0, bf0, bb0, mol, sv, fold_f, fold_b);
    h0_kernel<<<dim3(8, 64, 2), 256, 0, stream>>>(fold_f, fold_b, desc, sol, rf, h0f, h0b);
    gemm1_kernel<<<dim3(256), 512, 0, stream>>>(h0f, h0b, W1f_c, W1b_c, bf1, bb1, h1f, h1b);
    gemm_out_kernel<<<dim3(256), 512, 0, stream>>>(h1f, h1b, W2f_c, W2b_c, bf2, bb2, Wof, Wob, partial);
    finalize_kernel<<<dim3(32), 256, 0, stream>>>(partial, bof, bob, out);
}